// Round 11
// baseline (217.130 us; speedup 1.0000x reference)
//
#include <hip/hip_runtime.h>
#include <math.h>

#define NB 2
#define NL 2048
#define ND 1024
#define NH 16
#define NDH 64
#define NBL 4096   // NB*NL

typedef __attribute__((ext_vector_type(4)))  float f32x4;
typedef __attribute__((ext_vector_type(16))) float f32x16;
typedef __attribute__((ext_vector_type(8)))  short s16x8;
typedef __attribute__((ext_vector_type(4)))  short s16x4;

#define LOG2E 1.44269504088896f

__device__ __forceinline__ float fexp2(float x){
#if __has_builtin(__builtin_amdgcn_exp2f)
  return __builtin_amdgcn_exp2f(x);   // v_exp_f32: computes 2^x
#else
  return exp2f(x);
#endif
}

__device__ __forceinline__ unsigned short f2bf(float f){
  unsigned int u = __float_as_uint(f);
  u += 0x7FFF + ((u >> 16) & 1);   // round-to-nearest-even
  return (unsigned short)(u >> 16);
}

// pack two fp32 -> one dword of 2 bf16 (round-half-up: +0x8000)
__device__ __forceinline__ unsigned int pk2bf(float lo, float hi){
  return __builtin_amdgcn_perm(__float_as_uint(hi) + 0x8000u,
                               __float_as_uint(lo) + 0x8000u, 0x07060302u);
}

// ---- fused fp32->bf16 conversion (x + 4 weights) + rope tables, one launch ----
__global__ void cvt_all(const float* __restrict__ x,
                        const float* __restrict__ wq, const float* __restrict__ wk,
                        const float* __restrict__ wv, const float* __restrict__ wo,
                        unsigned short* __restrict__ xb,
                        unsigned short* __restrict__ wqb, unsigned short* __restrict__ wkb,
                        unsigned short* __restrict__ wvb, unsigned short* __restrict__ wob,
                        float2* __restrict__ qtab, float2* __restrict__ ktab){
  int i = blockIdx.x * blockDim.x + threadIdx.x;
  if (i < (1<<21)){                       // float4 conversion units
    const float* s; unsigned short* d; int off;
    if (i < (1<<20)) { s = x; d = xb; off = i; }
    else {
      int j = i - (1<<20); int w = j >> 18; off = j & ((1<<18)-1);
      s = (w==0)?wq:(w==1)?wk:(w==2)?wv:wo;
      d = (w==0)?wqb:(w==1)?wkb:(w==2)?wvb:wob;
    }
    float4 f = reinterpret_cast<const float4*>(s)[off];
    ushort4 r; r.x=f2bf(f.x); r.y=f2bf(f.y); r.z=f2bf(f.z); r.w=f2bf(f.w);
    reinterpret_cast<ushort4*>(d)[off] = r;
  } else {                                // xPos tables: 65536 entries
    int t = i - (1<<21);
    int l = t >> 5, k = t & 31;
    float half = 2.0f * (float)k;
    float inv_freq = 1.0f / powf(10000.0f, half / 64.0f);
    float fr = (float)l * inv_freq;
    float sv = (half + 0.4f * 64.0f) / (1.4f * 64.0f);
    float pw = ((float)l - 1024.0f) / 512.0f;
    float sc = powf(sv, pw);
    float cs = cosf(fr), sn = sinf(fr);
    qtab[t] = make_float2(cs * sc, sn * sc);
    ktab[t] = make_float2(cs / sc, sn / sc);
  }
}

// ---- fused QKV projection v3: 128x128 tiles (768 blocks = 3/CU), LDS-bounce epilogue.
//      grid z = 0 (q: rope*scale*log2e/32), 1 (k: rope/scale), 2 (v -> transposed) ----
__global__ __launch_bounds__(256, 3) void gemm_qkv(
    const unsigned short* __restrict__ A,
    const unsigned short* __restrict__ Wq, const float* __restrict__ bq,
    const unsigned short* __restrict__ Wk, const float* __restrict__ bk,
    const unsigned short* __restrict__ Wv, const float* __restrict__ bv,
    unsigned short* __restrict__ qb, unsigned short* __restrict__ kb,
    unsigned short* __restrict__ vtb,
    const float2* __restrict__ qtab, const float2* __restrict__ ktab)
{
  // union: main loop As[128][32] @0 (4096 sh) + Bs[128][32] @4096 (4096 sh);
  //        epilogue T[128][72] overlays @0 (9216 sh = 18 KB)
  __shared__ unsigned short smem[9216];

  const int mode = blockIdx.z;
  const unsigned short* W = (mode==0) ? Wq : (mode==1) ? Wk : Wv;
  const float* bias       = (mode==0) ? bq : (mode==1) ? bk : bv;

  const int tid  = threadIdx.x;
  const int wave = tid >> 6, lane = tid & 63;
  const int m16  = lane & 15, quad = lane >> 4;
  const int mrow = (wave & 1) * 64, ncol = (wave >> 1) * 64;
  const int rA   = lane >> 2, cA = (lane & 3) * 8;
  const int row0 = blockIdx.x * 128, col0 = blockIdx.y * 128;

  f32x4 acc[4][4] = {};

  for (int k0 = 0; k0 < ND; k0 += 32){
    __syncthreads();
#pragma unroll
    for (int i2 = 0; i2 < 2; i2++){
      const int c = wave * 2 + i2;                  // chunk: 16 rows x 64B
      const unsigned short* ga = A + (size_t)(row0 + c*16 + rA) * ND + k0 + cA;
      const unsigned short* gb = W + (size_t)(col0 + c*16 + rA) * ND + k0 + cA;
      __builtin_amdgcn_global_load_lds((const __attribute__((address_space(1))) void*)ga,
                                       (__attribute__((address_space(3))) void*)&smem[c*512], 16, 0, 0);
      __builtin_amdgcn_global_load_lds((const __attribute__((address_space(1))) void*)gb,
                                       (__attribute__((address_space(3))) void*)&smem[4096 + c*512], 16, 0, 0);
    }
    __syncthreads();
    s16x8 af[4], bf[4];
#pragma unroll
    for (int mt = 0; mt < 4; mt++)
      af[mt] = *reinterpret_cast<const s16x8*>(&smem[(mrow + mt*16 + m16)*32 + quad*8]);
#pragma unroll
    for (int nt = 0; nt < 4; nt++)
      bf[nt] = *reinterpret_cast<const s16x8*>(&smem[4096 + (ncol + nt*16 + m16)*32 + quad*8]);
#pragma unroll
    for (int mt = 0; mt < 4; mt++)
#pragma unroll
      for (int nt = 0; nt < 4; nt++)
        acc[mt][nt] = __builtin_amdgcn_mfma_f32_16x16x32_bf16(af[mt], bf[nt], acc[mt][nt], 0, 0, 0);
  }
  __syncthreads();   // main-loop reads done -> safe to overlay T

  const int b  = row0 >> 11, l0 = row0 & (NL - 1);

  // two 64-col halves; the owning wave-pair writes rope'd/biased bf16 into T, all copy out
#pragma unroll
  for (int h2 = 0; h2 < 2; h2++){
    if ((wave >> 1) == h2){
      if (mode == 2){
#pragma unroll
        for (int mt = 0; mt < 4; mt++)
#pragma unroll
          for (int nt = 0; nt < 4; nt++)
#pragma unroll
            for (int r = 0; r < 4; r++){
              int lrow = mrow + mt*16 + quad*4 + r;
              int dh   = nt*16 + m16;
              smem[lrow*72 + dh] = f2bf(acc[mt][nt][r] + bias[col0 + h2*64 + dh]);
            }
      } else {
        const float qscale = (mode == 0) ? (0.03125f * LOG2E) : 1.0f;
        const float2* tab  = (mode == 0) ? qtab : ktab;
#pragma unroll
        for (int mt = 0; mt < 4; mt++)
#pragma unroll
          for (int nt = 0; nt < 4; nt++)
#pragma unroll
            for (int r = 0; r < 4; r++){
              int lrow = mrow + mt*16 + quad*4 + r;
              int dh   = nt*16 + m16;
              float v  = acc[mt][nt][r] + bias[col0 + h2*64 + dh];
              float pv = __shfl_xor(v, 1);          // rotation partner (adjacent dh)
              float2 t = tab[(l0 + lrow)*32 + (dh >> 1)];
              float rh = (dh & 1) ? pv : -pv;
              smem[lrow*72 + dh] = f2bf((v * t.x + rh * t.y) * qscale);
            }
      }
    }
    __syncthreads();

    const int bh = b * NH + (col0 >> 6) + h2;
    if (mode == 2){
      // transposed copy-out: vtb[bh][dh][l]
#pragma unroll
      for (int j4 = 0; j4 < 4; j4++){
        int c = tid * 4 + j4;                 // 1024 chunks: 64 dh x 16 l-groups
        int d = c >> 4, seg = (c & 15) * 8;
        unsigned short tmp[8];
#pragma unroll
        for (int jj = 0; jj < 8; jj++) tmp[jj] = smem[(seg + jj)*72 + d];
        *reinterpret_cast<uint4*>(vtb + (size_t)(bh * NDH + d) * NL + l0 + seg) =
            *reinterpret_cast<uint4*>(tmp);
      }
    } else {
      // row-major copy-out: dst[bh][l][dh]
      unsigned short* dst = ((mode == 0) ? qb : kb) + ((size_t)bh * NL + l0) * NDH;
#pragma unroll
      for (int j = 0; j < 2; j++){
        int idx = j*256 + tid;                // 512 chunks: 128 l x 4 cg of 8... (64 dh = 8 cg? no: 64 dh = 8 groups of 8; 128 rows x 8 = 1024)
        (void)idx;
      }
      // 128 rows x 8 col-groups = 1024 uint4 chunks
#pragma unroll
      for (int j = 0; j < 4; j++){
        int idx = j*256 + tid;
        int row = idx >> 3, cg = (idx & 7) * 8;
        *reinterpret_cast<uint4*>(dst + row*NDH + cg) =
            *reinterpret_cast<const uint4*>(&smem[row*72 + cg]);
      }
    }
    __syncthreads();
  }
}

// ---- out projection: 128x64 tile, fp32 output ----
__global__ __launch_bounds__(256) void gemm_o(
    const unsigned short* __restrict__ A, const unsigned short* __restrict__ W,
    const float* __restrict__ bias, float* __restrict__ out)
{
  __shared__ unsigned short As[128][32];
  __shared__ unsigned short Bs[64][32];
  const int tid  = threadIdx.x;
  const int wave = tid >> 6, lane = tid & 63;
  const int m16  = lane & 15, quad = lane >> 4;
  const int mrow = (wave & 1) * 64, ncol = (wave >> 1) * 32;
  const int rA   = lane >> 2, cA = (lane & 3) * 8;
  const int row0 = blockIdx.x * 128, col0 = blockIdx.y * 64;

  f32x4 acc[4][2] = {};

  for (int k0 = 0; k0 < ND; k0 += 32){
    __syncthreads();
#pragma unroll
    for (int i3 = 0; i3 < 3; i3++){
      const int c = wave * 3 + i3;
      const unsigned short* g; unsigned short* l;
      if (c < 8){ g = A + (size_t)(row0 + c*16 + rA) * ND + k0 + cA;      l = &As[c*16][0]; }
      else      { g = W + (size_t)(col0 + (c-8)*16 + rA) * ND + k0 + cA;  l = &Bs[(c-8)*16][0]; }
      __builtin_amdgcn_global_load_lds((const __attribute__((address_space(1))) void*)g,
                                       (__attribute__((address_space(3))) void*)l, 16, 0, 0);
    }
    __syncthreads();
    s16x8 af[4], bf[2];
#pragma unroll
    for (int mt = 0; mt < 4; mt++) af[mt] = *reinterpret_cast<const s16x8*>(&As[mrow + mt*16 + m16][quad*8]);
#pragma unroll
    for (int nt = 0; nt < 2; nt++) bf[nt] = *reinterpret_cast<const s16x8*>(&Bs[ncol + nt*16 + m16][quad*8]);
#pragma unroll
    for (int mt = 0; mt < 4; mt++)
#pragma unroll
      for (int nt = 0; nt < 2; nt++)
        acc[mt][nt] = __builtin_amdgcn_mfma_f32_16x16x32_bf16(af[mt], bf[nt], acc[mt][nt], 0, 0, 0);
  }

#pragma unroll
  for (int mt = 0; mt < 4; mt++)
#pragma unroll
    for (int nt = 0; nt < 2; nt++)
#pragma unroll
      for (int r = 0; r < 4; r++){
        int grow = row0 + mrow + mt*16 + quad*4 + r;
        int gcol = col0 + ncol + nt*16 + m16;
        out[(size_t)grow * ND + gcol] = acc[mt][nt][r] + bias[gcol];
      }
}

// ---- flash attention v7b: in-block split-K. 128 q/block; waves 0-1 take keys [0,1024),
//      waves 2-3 keys [1024,2048) (64 q/wave). Double-buffered K/V LDS per half (64 KB),
//      register-fed PV, partials combined through LDS in the epilogue -> final output. ----
__global__ __launch_bounds__(256, 2) void attn_kernel(
    const unsigned short* __restrict__ qb,
    const unsigned short* __restrict__ kb,
    const unsigned short* __restrict__ vtb,   // [bh][dh][l]
    unsigned short* __restrict__ ob)          // final inter[b, l, h*64+dh]
{
  // per half (stride 16384 sh): K b0 @+0, K b1 @+4096, V b0 @+8192, V b1 @+12288
  // epilogue overlays: Osb bf16 [128][72] @0 (9216 sh); lsb float[2][2][2][32] @20480 sh
  __shared__ unsigned short smem[32768];   // 64 KB
  const int tid  = threadIdx.x;
  const int wave = tid >> 6, lane = tid & 63;
  const int l31  = lane & 31, g = lane >> 5;
  const int half = wave >> 1, w2 = wave & 1;
  const int bh   = blockIdx.y;
  const int q0   = blockIdx.x * 128;
  const int khalf = half * (NL / 2);
  const unsigned short* Q  = qb  + (size_t)bh * NL * NDH;
  const unsigned short* K  = kb  + (size_t)bh * NL * NDH;
  const unsigned short* Vt = vtb + (size_t)bh * NDH * NL;

  // Q B-frags (32x32x16): wave covers 64 q rows (two 32-q subtiles)
  s16x8 qf[2][4];
#pragma unroll
  for (int q2 = 0; q2 < 2; q2++)
#pragma unroll
    for (int s = 0; s < 4; s++)
      qf[q2][s] = *reinterpret_cast<const s16x8*>(
          Q + (size_t)(q0 + w2*64 + q2*32 + l31) * NDH + s*16 + g*8);

  // staging: each half (128 threads) stages its own K/V tile: 4 passes of 16 rows
  const int ht = tid & 127;
  const int rr = ht >> 3, cc = ht & 7;           // rr 0..15, cc 0..7
  const int HB = half * 16384;
  const int so0 = rr*64 + ((cc ^ (rr & 7)) * 8); // + p*1024 per pass

  uint4 kr[4], vr[4];
#pragma unroll
  for (int p = 0; p < 4; p++){
    kr[p] = *reinterpret_cast<const uint4*>(K  + (size_t)(khalf + rr + 16*p) * NDH + cc*8);
    vr[p] = *reinterpret_cast<const uint4*>(Vt + (size_t)(rr + 16*p) * NL + khalf + cc*8);
  }
#pragma unroll
  for (int p = 0; p < 4; p++){
    *reinterpret_cast<uint4*>(&smem[HB + so0 + p*1024])        = kr[p];
    *reinterpret_cast<uint4*>(&smem[HB + 8192 + so0 + p*1024]) = vr[p];
  }
#pragma unroll
  for (int p = 0; p < 4; p++){
    kr[p] = *reinterpret_cast<const uint4*>(K  + (size_t)(khalf + 64 + rr + 16*p) * NDH + cc*8);
    vr[p] = *reinterpret_cast<const uint4*>(Vt + (size_t)(rr + 16*p) * NL + khalf + 64 + cc*8);
  }
  __syncthreads();

  float ls[2] = {0.f, 0.f};
  f32x16 ot[2][2] = {};   // [dh-tile mt][q2]
  const int key7 = l31 & 7;

  for (int kt = 0; kt < 16; kt++){
    const int cur = HB + (kt & 1) * 4096;
    const int nxt = HB + (((kt & 1) ^ 1)) * 4096;
    if (kt < 15){
#pragma unroll
      for (int p = 0; p < 4; p++){
        *reinterpret_cast<uint4*>(&smem[nxt + so0 + p*1024])        = kr[p];
        *reinterpret_cast<uint4*>(&smem[nxt + 8192 + so0 + p*1024]) = vr[p];
      }
    }
    if (kt < 14){
      const int k0n = khalf + (kt + 2) * 64;
#pragma unroll
      for (int p = 0; p < 4; p++){
        kr[p] = *reinterpret_cast<const uint4*>(K  + (size_t)(k0n + rr + 16*p) * NDH + cc*8);
        vr[p] = *reinterpret_cast<const uint4*>(Vt + (size_t)(rr + 16*p) * NL + k0n + cc*8);
      }
    }

    const unsigned short* Kb = &smem[cur];
    const unsigned short* Vb = &smem[cur + 8192];

    // St[key][q] via 32x32x16 for both q2 subtiles (kf shared), then exp2+pack
    uint2 pmat[2][8];
#pragma unroll
    for (int t = 0; t < 2; t++){
      f32x16 st0 = {}, st1 = {};
#pragma unroll
      for (int s = 0; s < 4; s++){
        const int cg = (2*s + g) ^ key7;
        s16x8 kf = *reinterpret_cast<const s16x8*>(&Kb[(t*32 + l31)*64 + cg*8]);
        st0 = __builtin_amdgcn_mfma_f32_32x32x16_bf16(kf, qf[0][s], st0, 0, 0, 0);
        st1 = __builtin_amdgcn_mfma_f32_32x32x16_bf16(kf, qf[1][s], st1, 0, 0, 0);
      }
#pragma unroll
      for (int j = 0; j < 4; j++){
        float a0 = fexp2(st0[4*j]),   a1 = fexp2(st0[4*j+1]);
        float a2 = fexp2(st0[4*j+2]), a3 = fexp2(st0[4*j+3]);
        ls[0] += (a0 + a1) + (a2 + a3);
        pmat[0][t*4+j].x = pk2bf(a0, a1);
        pmat[0][t*4+j].y = pk2bf(a2, a3);
        float b0 = fexp2(st1[4*j]),   b1 = fexp2(st1[4*j+1]);
        float b2 = fexp2(st1[4*j+2]), b3 = fexp2(st1[4*j+3]);
        ls[1] += (b0 + b1) + (b2 + b3);
        pmat[1][t*4+j].x = pk2bf(b0, b1);
        pmat[1][t*4+j].y = pk2bf(b2, b3);
      }
    }

    // Ot += V · P^T via 32x32x8 (B-operand = P direct from registers)
#pragma unroll
    for (int mt = 0; mt < 2; mt++){
      const int dh = mt*32 + l31;
#pragma unroll
      for (int s = 0; s < 8; s++){
        const int cg = s ^ (dh & 7);
        s16x4 vf = *reinterpret_cast<const s16x4*>(&Vb[dh*64 + cg*8 + g*4]);
        ot[mt][0] = __builtin_amdgcn_mfma_f32_32x32x8bf16_1k(
            vf, *reinterpret_cast<s16x4*>(&pmat[0][s]), ot[mt][0], 0, 0, 0);
        ot[mt][1] = __builtin_amdgcn_mfma_f32_32x32x8bf16_1k(
            vf, *reinterpret_cast<s16x4*>(&pmat[1][s]), ot[mt][1], 0, 0, 0);
      }
    }
    __syncthreads();
  }

  // ---- epilogue: combine halves through LDS ----
  float* lsb = reinterpret_cast<float*>(&smem[20480]);
  if (half == 0){
    // bf16 partial O + per-lane fp32 l partials
#pragma unroll
    for (int q2 = 0; q2 < 2; q2++)
      lsb[((w2*2 + q2)*2 + g)*32 + l31] = ls[q2];
#pragma unroll
    for (int mt = 0; mt < 2; mt++)
#pragma unroll
      for (int q2 = 0; q2 < 2; q2++)
#pragma unroll
        for (int s = 0; s < 4; s++){
          uint2 pk;
          pk.x = pk2bf(ot[mt][q2][4*s],     ot[mt][q2][4*s + 1]);
          pk.y = pk2bf(ot[mt][q2][4*s + 2], ot[mt][q2][4*s + 3]);
          *reinterpret_cast<uint2*>(&smem[(w2*64 + q2*32 + l31)*72 + mt*32 + s*8 + g*4]) = pk;
        }
  }
  __syncthreads();
  if (half == 1){
    float linv[2];
#pragma unroll
    for (int q2 = 0; q2 < 2; q2++){
      float t = ls[q2] + __shfl_xor(ls[q2], 32)
              + lsb[((w2*2 + q2)*2 + 0)*32 + l31]
              + lsb[((w2*2 + q2)*2 + 1)*32 + l31];
      linv[q2] = 1.0f / t;
    }
#pragma unroll
    for (int mt = 0; mt < 2; mt++)
#pragma unroll
      for (int q2 = 0; q2 < 2; q2++)
#pragma unroll
        for (int s = 0; s < 4; s++){
          unsigned short* ad = &smem[(w2*64 + q2*32 + l31)*72 + mt*32 + s*8 + g*4];
          uint2 u = *reinterpret_cast<const uint2*>(ad);
          float p0 = __uint_as_float(u.x << 16)          + ot[mt][q2][4*s];
          float p1 = __uint_as_float(u.x & 0xFFFF0000u)  + ot[mt][q2][4*s + 1];
          float p2 = __uint_as_float(u.y << 16)          + ot[mt][q2][4*s + 2];
          float p3 = __uint_as_float(u.y & 0xFFFF0000u)  + ot[mt][q2][4*s + 3];
          uint2 pk;
          pk.x = pk2bf(p0 * linv[q2], p1 * linv[q2]);
          pk.y = pk2bf(p2 * linv[q2], p3 * linv[q2]);
          *reinterpret_cast<uint2*>(ad) = pk;
        }
  }
  __syncthreads();

  // coalesced final write-out: inter[b, l, h*64+dh]; 128 rows x 8 cg = 1024 uint4
  const int bb = bh >> 4, h = bh & 15;
#pragma unroll
  for (int j = 0; j < 4; j++){
    int idx = j*256 + tid;
    int row = idx >> 3, cg2 = (idx & 7) * 8;
    *reinterpret_cast<uint4*>(ob + ((size_t)(bb*NL + q0 + row)) * ND + h*NDH + cg2) =
        *reinterpret_cast<const uint4*>(&smem[row*72 + cg2]);
  }
}

extern "C" void kernel_launch(void* const* d_in, const int* in_sizes, int n_in,
                              void* d_out, int out_size, void* d_ws, size_t ws_size,
                              hipStream_t stream)
{
  (void)in_sizes; (void)n_in; (void)out_size; (void)ws_size;
  const float* x  = (const float*)d_in[0];
  const float* Wq = (const float*)d_in[1];
  const float* bq = (const float*)d_in[2];
  const float* Wk = (const float*)d_in[3];
  const float* bk = (const float*)d_in[4];
  const float* Wv = (const float*)d_in[5];
  const float* bv = (const float*)d_in[6];
  const float* Wo = (const float*)d_in[7];
  const float* bo = (const float*)d_in[8];
  float* out = (float*)d_out;

  char* p = (char*)d_ws;
  unsigned short* xb   = (unsigned short*)p; p += (size_t)NBL*ND*2;
  unsigned short* wqb  = (unsigned short*)p; p += (size_t)ND*ND*2;
  unsigned short* wkb  = (unsigned short*)p; p += (size_t)ND*ND*2;
  unsigned short* wvb  = (unsigned short*)p; p += (size_t)ND*ND*2;
  unsigned short* wob  = (unsigned short*)p; p += (size_t)ND*ND*2;
  unsigned short* qbuf = (unsigned short*)p; p += (size_t)NBL*ND*2;
  unsigned short* kbuf = (unsigned short*)p; p += (size_t)NBL*ND*2;
  unsigned short* vtb  = (unsigned short*)p; p += (size_t)NBL*ND*2;
  unsigned short* ibuf = (unsigned short*)p; p += (size_t)NBL*ND*2;
  float2* qtab = (float2*)p; p += (size_t)NL*32*8;
  float2* ktab = (float2*)p; p += (size_t)NL*32*8;

  // 2M cvt units + 64K rope units = 8448 blocks
  hipLaunchKernelGGL(cvt_all, dim3(8448), dim3(256), 0, stream,
                     x, Wq, Wk, Wv, Wo, xb, wqb, wkb, wvb, wob, qtab, ktab);

  // NOTE the reference's swap: k uses (Wv,bv), v uses (Wk,bk)
  hipLaunchKernelGGL(gemm_qkv, dim3(NBL/128, ND/128, 3), dim3(256), 0, stream,
                     xb, wqb, bq, wvb, bv, wkb, bk, qbuf, kbuf, vtb, qtab, ktab);

  hipLaunchKernelGGL(attn_kernel, dim3(NL/128, NB*NH), dim3(256), 0, stream,
                     qbuf, kbuf, vtb, ibuf);

  hipLaunchKernelGGL(gemm_o, dim3(NBL/128, ND/64), dim3(256), 0, stream, ibuf, wob, bo, out);
}

// Round 12
// 199.772 us; speedup vs baseline: 1.0869x; 1.0869x over previous
//
#include <hip/hip_runtime.h>
#include <math.h>

#define NB 2
#define NL 2048
#define ND 1024
#define NH 16
#define NDH 64
#define NBL 4096   // NB*NL

typedef __attribute__((ext_vector_type(4)))  float f32x4;
typedef __attribute__((ext_vector_type(16))) float f32x16;
typedef __attribute__((ext_vector_type(8)))  short s16x8;
typedef __attribute__((ext_vector_type(4)))  short s16x4;

#define LOG2E 1.44269504088896f

__device__ __forceinline__ float fexp2(float x){
#if __has_builtin(__builtin_amdgcn_exp2f)
  return __builtin_amdgcn_exp2f(x);   // v_exp_f32: computes 2^x
#else
  return exp2f(x);
#endif
}

__device__ __forceinline__ unsigned short f2bf(float f){
  unsigned int u = __float_as_uint(f);
  u += 0x7FFF + ((u >> 16) & 1);   // round-to-nearest-even
  return (unsigned short)(u >> 16);
}

// pack two fp32 -> one dword of 2 bf16 (round-half-up: +0x8000)
__device__ __forceinline__ unsigned int pk2bf(float lo, float hi){
  return __builtin_amdgcn_perm(__float_as_uint(hi) + 0x8000u,
                               __float_as_uint(lo) + 0x8000u, 0x07060302u);
}

// ---- fused fp32->bf16 conversion (x + 4 weights) + rope tables, one launch ----
__global__ void cvt_all(const float* __restrict__ x,
                        const float* __restrict__ wq, const float* __restrict__ wk,
                        const float* __restrict__ wv, const float* __restrict__ wo,
                        unsigned short* __restrict__ xb,
                        unsigned short* __restrict__ wqb, unsigned short* __restrict__ wkb,
                        unsigned short* __restrict__ wvb, unsigned short* __restrict__ wob,
                        float2* __restrict__ qtab, float2* __restrict__ ktab){
  int i = blockIdx.x * blockDim.x + threadIdx.x;
  if (i < (1<<21)){                       // float4 conversion units
    const float* s; unsigned short* d; int off;
    if (i < (1<<20)) { s = x; d = xb; off = i; }
    else {
      int j = i - (1<<20); int w = j >> 18; off = j & ((1<<18)-1);
      s = (w==0)?wq:(w==1)?wk:(w==2)?wv:wo;
      d = (w==0)?wqb:(w==1)?wkb:(w==2)?wvb:wob;
    }
    float4 f = reinterpret_cast<const float4*>(s)[off];
    ushort4 r; r.x=f2bf(f.x); r.y=f2bf(f.y); r.z=f2bf(f.z); r.w=f2bf(f.w);
    reinterpret_cast<ushort4*>(d)[off] = r;
  } else {                                // xPos tables: 65536 entries
    int t = i - (1<<21);
    int l = t >> 5, k = t & 31;
    float half = 2.0f * (float)k;
    float inv_freq = 1.0f / powf(10000.0f, half / 64.0f);
    float fr = (float)l * inv_freq;
    float sv = (half + 0.4f * 64.0f) / (1.4f * 64.0f);
    float pw = ((float)l - 1024.0f) / 512.0f;
    float sc = powf(sv, pw);
    float cs = cosf(fr), sn = sinf(fr);
    qtab[t] = make_float2(cs * sc, sn * sc);
    ktab[t] = make_float2(cs / sc, sn / sc);
  }
}

// ---- fused QKV projection: 128x128 tiles (768 blocks = 3/CU), LDS-bounce epilogue.
//      grid z = 0 (q: rope*scale*log2e/32), 1 (k: rope/scale), 2 (v -> transposed) ----
__global__ __launch_bounds__(256, 3) void gemm_qkv(
    const unsigned short* __restrict__ A,
    const unsigned short* __restrict__ Wq, const float* __restrict__ bq,
    const unsigned short* __restrict__ Wk, const float* __restrict__ bk,
    const unsigned short* __restrict__ Wv, const float* __restrict__ bv,
    unsigned short* __restrict__ qb, unsigned short* __restrict__ kb,
    unsigned short* __restrict__ vtb,
    const float2* __restrict__ qtab, const float2* __restrict__ ktab)
{
  // union: main loop As[128][32] @0 (4096 sh) + Bs[128][32] @4096 (4096 sh);
  //        epilogue T[128][72] overlays @0 (9216 sh = 18 KB)
  __shared__ unsigned short smem[9216];

  const int mode = blockIdx.z;
  const unsigned short* W = (mode==0) ? Wq : (mode==1) ? Wk : Wv;
  const float* bias       = (mode==0) ? bq : (mode==1) ? bk : bv;

  const int tid  = threadIdx.x;
  const int wave = tid >> 6, lane = tid & 63;
  const int m16  = lane & 15, quad = lane >> 4;
  const int mrow = (wave & 1) * 64, ncol = (wave >> 1) * 64;
  const int rA   = lane >> 2, cA = (lane & 3) * 8;
  const int row0 = blockIdx.x * 128, col0 = blockIdx.y * 128;

  f32x4 acc[4][4] = {};

  for (int k0 = 0; k0 < ND; k0 += 32){
    __syncthreads();
#pragma unroll
    for (int i2 = 0; i2 < 2; i2++){
      const int c = wave * 2 + i2;                  // chunk: 16 rows x 64B
      const unsigned short* ga = A + (size_t)(row0 + c*16 + rA) * ND + k0 + cA;
      const unsigned short* gb = W + (size_t)(col0 + c*16 + rA) * ND + k0 + cA;
      __builtin_amdgcn_global_load_lds((const __attribute__((address_space(1))) void*)ga,
                                       (__attribute__((address_space(3))) void*)&smem[c*512], 16, 0, 0);
      __builtin_amdgcn_global_load_lds((const __attribute__((address_space(1))) void*)gb,
                                       (__attribute__((address_space(3))) void*)&smem[4096 + c*512], 16, 0, 0);
    }
    __syncthreads();
    s16x8 af[4], bf[4];
#pragma unroll
    for (int mt = 0; mt < 4; mt++)
      af[mt] = *reinterpret_cast<const s16x8*>(&smem[(mrow + mt*16 + m16)*32 + quad*8]);
#pragma unroll
    for (int nt = 0; nt < 4; nt++)
      bf[nt] = *reinterpret_cast<const s16x8*>(&smem[4096 + (ncol + nt*16 + m16)*32 + quad*8]);
#pragma unroll
    for (int mt = 0; mt < 4; mt++)
#pragma unroll
      for (int nt = 0; nt < 4; nt++)
        acc[mt][nt] = __builtin_amdgcn_mfma_f32_16x16x32_bf16(af[mt], bf[nt], acc[mt][nt], 0, 0, 0);
  }
  __syncthreads();   // main-loop reads done -> safe to overlay T

  const int b  = row0 >> 11, l0 = row0 & (NL - 1);

  // two 64-col halves; the owning wave-pair writes rope'd/biased bf16 into T, all copy out
#pragma unroll
  for (int h2 = 0; h2 < 2; h2++){
    if ((wave >> 1) == h2){
      if (mode == 2){
#pragma unroll
        for (int mt = 0; mt < 4; mt++)
#pragma unroll
          for (int nt = 0; nt < 4; nt++)
#pragma unroll
            for (int r = 0; r < 4; r++){
              int lrow = mrow + mt*16 + quad*4 + r;
              int dh   = nt*16 + m16;
              smem[lrow*72 + dh] = f2bf(acc[mt][nt][r] + bias[col0 + h2*64 + dh]);
            }
      } else {
        const float qscale = (mode == 0) ? (0.03125f * LOG2E) : 1.0f;
        const float2* tab  = (mode == 0) ? qtab : ktab;
#pragma unroll
        for (int mt = 0; mt < 4; mt++)
#pragma unroll
          for (int nt = 0; nt < 4; nt++)
#pragma unroll
            for (int r = 0; r < 4; r++){
              int lrow = mrow + mt*16 + quad*4 + r;
              int dh   = nt*16 + m16;
              float v  = acc[mt][nt][r] + bias[col0 + h2*64 + dh];
              float pv = __shfl_xor(v, 1);          // rotation partner (adjacent dh)
              float2 t = tab[(l0 + lrow)*32 + (dh >> 1)];
              float rh = (dh & 1) ? pv : -pv;
              smem[lrow*72 + dh] = f2bf((v * t.x + rh * t.y) * qscale);
            }
      }
    }
    __syncthreads();

    const int bh = b * NH + (col0 >> 6) + h2;
    if (mode == 2){
      // transposed copy-out: vtb[bh][dh][l]
#pragma unroll
      for (int j4 = 0; j4 < 4; j4++){
        int c = tid * 4 + j4;                 // 1024 chunks: 64 dh x 16 l-groups
        int d = c >> 4, seg = (c & 15) * 8;
        unsigned short tmp[8];
#pragma unroll
        for (int jj = 0; jj < 8; jj++) tmp[jj] = smem[(seg + jj)*72 + d];
        *reinterpret_cast<uint4*>(vtb + (size_t)(bh * NDH + d) * NL + l0 + seg) =
            *reinterpret_cast<uint4*>(tmp);
      }
    } else {
      // row-major copy-out: dst[bh][l][dh]; 128 rows x 8 col-groups = 1024 uint4
      unsigned short* dst = ((mode == 0) ? qb : kb) + ((size_t)bh * NL + l0) * NDH;
#pragma unroll
      for (int j = 0; j < 4; j++){
        int idx = j*256 + tid;
        int row = idx >> 3, cg = (idx & 7) * 8;
        *reinterpret_cast<uint4*>(dst + row*NDH + cg) =
            *reinterpret_cast<const uint4*>(&smem[row*72 + cg]);
      }
    }
    __syncthreads();
  }
}

// ---- out projection: 128x64 tile, fp32 output ----
__global__ __launch_bounds__(256) void gemm_o(
    const unsigned short* __restrict__ A, const unsigned short* __restrict__ W,
    const float* __restrict__ bias, float* __restrict__ out)
{
  __shared__ unsigned short As[128][32];
  __shared__ unsigned short Bs[64][32];
  const int tid  = threadIdx.x;
  const int wave = tid >> 6, lane = tid & 63;
  const int m16  = lane & 15, quad = lane >> 4;
  const int mrow = (wave & 1) * 64, ncol = (wave >> 1) * 32;
  const int rA   = lane >> 2, cA = (lane & 3) * 8;
  const int row0 = blockIdx.x * 128, col0 = blockIdx.y * 64;

  f32x4 acc[4][2] = {};

  for (int k0 = 0; k0 < ND; k0 += 32){
    __syncthreads();
#pragma unroll
    for (int i3 = 0; i3 < 3; i3++){
      const int c = wave * 3 + i3;
      const unsigned short* g; unsigned short* l;
      if (c < 8){ g = A + (size_t)(row0 + c*16 + rA) * ND + k0 + cA;      l = &As[c*16][0]; }
      else      { g = W + (size_t)(col0 + (c-8)*16 + rA) * ND + k0 + cA;  l = &Bs[(c-8)*16][0]; }
      __builtin_amdgcn_global_load_lds((const __attribute__((address_space(1))) void*)g,
                                       (__attribute__((address_space(3))) void*)l, 16, 0, 0);
    }
    __syncthreads();
    s16x8 af[4], bf[2];
#pragma unroll
    for (int mt = 0; mt < 4; mt++) af[mt] = *reinterpret_cast<const s16x8*>(&As[mrow + mt*16 + m16][quad*8]);
#pragma unroll
    for (int nt = 0; nt < 2; nt++) bf[nt] = *reinterpret_cast<const s16x8*>(&Bs[ncol + nt*16 + m16][quad*8]);
#pragma unroll
    for (int mt = 0; mt < 4; mt++)
#pragma unroll
      for (int nt = 0; nt < 2; nt++)
        acc[mt][nt] = __builtin_amdgcn_mfma_f32_16x16x32_bf16(af[mt], bf[nt], acc[mt][nt], 0, 0, 0);
  }

#pragma unroll
  for (int mt = 0; mt < 4; mt++)
#pragma unroll
    for (int nt = 0; nt < 2; nt++)
#pragma unroll
      for (int r = 0; r < 4; r++){
        int grow = row0 + mrow + mt*16 + quad*4 + r;
        int gcol = col0 + ncol + nt*16 + m16;
        out[(size_t)grow * ND + gcol] = acc[mt][nt][r] + bias[gcol];
      }
}

// ---- flash attention v6 (measured-good): cross-block split-K (z=2), 256 q/block,
//      64 q/wave, double-buffered K/V LDS, register-fed PV, linear partials ----
__global__ __launch_bounds__(256, 2) void attn_kernel(
    const unsigned short* __restrict__ qb,
    const unsigned short* __restrict__ kb,
    const unsigned short* __restrict__ vtb,   // [bh][dh][l]
    unsigned short* __restrict__ opart,       // [2][b][l][h*64+dh] bf16, unnormalized
    float* __restrict__ lsum)                 // [2][bh][q] fp32
{
  __shared__ unsigned short smem[256 * 72];
  const int tid  = threadIdx.x;
  const int wave = tid >> 6, lane = tid & 63;
  const int l31  = lane & 31, g = lane >> 5;
  const int bh   = blockIdx.y;
  const int z    = blockIdx.z;
  const int q0   = blockIdx.x * 256;
  const int kbase = z * (NL / 2);
  const unsigned short* Q  = qb  + (size_t)bh * NL * NDH;
  const unsigned short* K  = kb  + (size_t)bh * NL * NDH;
  const unsigned short* Vt = vtb + (size_t)bh * NDH * NL;

  s16x8 qf[2][4];
#pragma unroll
  for (int q2 = 0; q2 < 2; q2++)
#pragma unroll
    for (int s = 0; s < 4; s++)
      qf[q2][s] = *reinterpret_cast<const s16x8*>(
          Q + (size_t)(q0 + wave*64 + q2*32 + l31) * NDH + s*16 + g*8);

  const int r0 = tid >> 3, c0 = tid & 7;
  const int r1 = r0 + 32;
  const int so0 = r0*64 + ((c0 ^ (r0 & 7)) * 8);
  const int so1 = r1*64 + ((c0 ^ (r1 & 7)) * 8);

  uint4 kreg0 = *reinterpret_cast<const uint4*>(K  + (size_t)(kbase + r0) * NDH + c0*8);
  uint4 kreg1 = *reinterpret_cast<const uint4*>(K  + (size_t)(kbase + r1) * NDH + c0*8);
  uint4 vreg0 = *reinterpret_cast<const uint4*>(Vt + (size_t)r0 * NL + kbase + c0*8);
  uint4 vreg1 = *reinterpret_cast<const uint4*>(Vt + (size_t)r1 * NL + kbase + c0*8);
  *reinterpret_cast<uint4*>(&smem[so0])         = kreg0;
  *reinterpret_cast<uint4*>(&smem[so1])         = kreg1;
  *reinterpret_cast<uint4*>(&smem[8192 + so0])  = vreg0;
  *reinterpret_cast<uint4*>(&smem[8192 + so1])  = vreg1;
  kreg0 = *reinterpret_cast<const uint4*>(K  + (size_t)(kbase + 64 + r0) * NDH + c0*8);
  kreg1 = *reinterpret_cast<const uint4*>(K  + (size_t)(kbase + 64 + r1) * NDH + c0*8);
  vreg0 = *reinterpret_cast<const uint4*>(Vt + (size_t)r0 * NL + kbase + 64 + c0*8);
  vreg1 = *reinterpret_cast<const uint4*>(Vt + (size_t)r1 * NL + kbase + 64 + c0*8);
  __syncthreads();

  float ls[2] = {0.f, 0.f};
  f32x16 ot[2][2] = {};
  const int key7 = l31 & 7;

  for (int kt = 0; kt < 16; kt++){
    const int cur = (kt & 1) * 4096;
    const int nxt = 4096 - cur;
    if (kt < 15){
      *reinterpret_cast<uint4*>(&smem[nxt + so0])        = kreg0;
      *reinterpret_cast<uint4*>(&smem[nxt + so1])        = kreg1;
      *reinterpret_cast<uint4*>(&smem[8192 + nxt + so0]) = vreg0;
      *reinterpret_cast<uint4*>(&smem[8192 + nxt + so1]) = vreg1;
    }
    if (kt < 14){
      const int k0n = kbase + (kt + 2) * 64;
      kreg0 = *reinterpret_cast<const uint4*>(K  + (size_t)(k0n + r0) * NDH + c0*8);
      kreg1 = *reinterpret_cast<const uint4*>(K  + (size_t)(k0n + r1) * NDH + c0*8);
      vreg0 = *reinterpret_cast<const uint4*>(Vt + (size_t)r0 * NL + k0n + c0*8);
      vreg1 = *reinterpret_cast<const uint4*>(Vt + (size_t)r1 * NL + k0n + c0*8);
    }

    const unsigned short* Kb = &smem[cur];
    const unsigned short* Vb = &smem[8192 + cur];

    uint2 pmat[2][8];
#pragma unroll
    for (int t = 0; t < 2; t++){
      f32x16 st0 = {}, st1 = {};
#pragma unroll
      for (int s = 0; s < 4; s++){
        const int cg = (2*s + g) ^ key7;
        s16x8 kf = *reinterpret_cast<const s16x8*>(&Kb[(t*32 + l31)*64 + cg*8]);
        st0 = __builtin_amdgcn_mfma_f32_32x32x16_bf16(kf, qf[0][s], st0, 0, 0, 0);
        st1 = __builtin_amdgcn_mfma_f32_32x32x16_bf16(kf, qf[1][s], st1, 0, 0, 0);
      }
#pragma unroll
      for (int j = 0; j < 4; j++){
        float a0 = fexp2(st0[4*j]),   a1 = fexp2(st0[4*j+1]);
        float a2 = fexp2(st0[4*j+2]), a3 = fexp2(st0[4*j+3]);
        ls[0] += (a0 + a1) + (a2 + a3);
        pmat[0][t*4+j].x = pk2bf(a0, a1);
        pmat[0][t*4+j].y = pk2bf(a2, a3);
        float b0 = fexp2(st1[4*j]),   b1 = fexp2(st1[4*j+1]);
        float b2 = fexp2(st1[4*j+2]), b3 = fexp2(st1[4*j+3]);
        ls[1] += (b0 + b1) + (b2 + b3);
        pmat[1][t*4+j].x = pk2bf(b0, b1);
        pmat[1][t*4+j].y = pk2bf(b2, b3);
      }
    }

#pragma unroll
    for (int mt = 0; mt < 2; mt++){
      const int dh = mt*32 + l31;
#pragma unroll
      for (int s = 0; s < 8; s++){
        const int cg = s ^ (dh & 7);
        s16x4 vf = *reinterpret_cast<const s16x4*>(&Vb[dh*64 + cg*8 + g*4]);
        ot[mt][0] = __builtin_amdgcn_mfma_f32_32x32x8bf16_1k(
            vf, *reinterpret_cast<s16x4*>(&pmat[0][s]), ot[mt][0], 0, 0, 0);
        ot[mt][1] = __builtin_amdgcn_mfma_f32_32x32x8bf16_1k(
            vf, *reinterpret_cast<s16x4*>(&pmat[1][s]), ot[mt][1], 0, 0, 0);
      }
    }
    __syncthreads();
  }

#pragma unroll
  for (int q2 = 0; q2 < 2; q2++){
    float t = ls[q2] + __shfl_xor(ls[q2], 32);
    if (g == 0)
      lsum[((size_t)z * NB * NH + bh) * NL + q0 + wave*64 + q2*32 + l31] = t;
  }

#pragma unroll
  for (int mt = 0; mt < 2; mt++)
#pragma unroll
    for (int q2 = 0; q2 < 2; q2++)
#pragma unroll
      for (int s = 0; s < 4; s++){
        uint2 pk;
        pk.x = pk2bf(ot[mt][q2][4*s],     ot[mt][q2][4*s + 1]);
        pk.y = pk2bf(ot[mt][q2][4*s + 2], ot[mt][q2][4*s + 3]);
        *reinterpret_cast<uint2*>(&smem[(wave*64 + q2*32 + l31)*72 + mt*32 + s*8 + g*4]) = pk;
      }
  __syncthreads();

  const int bb = bh >> 4, h = bh & 15;
  unsigned short* od = opart + (size_t)z * NBL * ND;
#pragma unroll
  for (int j = 0; j < 8; j++){
    int idx = j*256 + tid;
    int row = idx >> 3, cg2 = (idx & 7) * 8;
    *reinterpret_cast<uint4*>(od + ((size_t)(bb*NL + q0 + row)) * ND + h*NDH + cg2) =
        *reinterpret_cast<const uint4*>(&smem[row*72 + cg2]);
  }
}

// ---- combine: out = (O0 + O1) / (l0 + l1), written in-place over opart[0] ----
__device__ __forceinline__ unsigned int comb2(unsigned int a, unsigned int b, float inv){
  float alo = __uint_as_float(a << 16), ahi = __uint_as_float(a & 0xFFFF0000u);
  float blo = __uint_as_float(b << 16), bhi = __uint_as_float(b & 0xFFFF0000u);
  return pk2bf((alo + blo) * inv, (ahi + bhi) * inv);
}

__global__ __launch_bounds__(256) void attn_combine(
    unsigned short* __restrict__ opart, const float* __restrict__ lsum)
{
  int idx = blockIdx.x * 256 + threadIdx.x;   // uint4 (8 bf16) units, 524288 total
  int row = idx >> 7;            // b*2048 + l
  int col8 = idx & 127;
  int h = col8 >> 3;
  int b = row >> 11, l = row & (NL - 1);
  int bh = b * NH + h;
  float l0 = lsum[(size_t)bh * NL + l];
  float l1 = lsum[(size_t)(NB*NH + bh) * NL + l];
  float inv = 1.0f / (l0 + l1);
  uint4 u0 = reinterpret_cast<const uint4*>(opart)[idx];
  uint4 u1 = reinterpret_cast<const uint4*>(opart + (size_t)NBL * ND)[idx];
  uint4 o;
  o.x = comb2(u0.x, u1.x, inv);
  o.y = comb2(u0.y, u1.y, inv);
  o.z = comb2(u0.z, u1.z, inv);
  o.w = comb2(u0.w, u1.w, inv);
  reinterpret_cast<uint4*>(opart)[idx] = o;
}

extern "C" void kernel_launch(void* const* d_in, const int* in_sizes, int n_in,
                              void* d_out, int out_size, void* d_ws, size_t ws_size,
                              hipStream_t stream)
{
  (void)in_sizes; (void)n_in; (void)out_size; (void)ws_size;
  const float* x  = (const float*)d_in[0];
  const float* Wq = (const float*)d_in[1];
  const float* bq = (const float*)d_in[2];
  const float* Wk = (const float*)d_in[3];
  const float* bk = (const float*)d_in[4];
  const float* Wv = (const float*)d_in[5];
  const float* bv = (const float*)d_in[6];
  const float* Wo = (const float*)d_in[7];
  const float* bo = (const float*)d_in[8];
  float* out = (float*)d_out;

  char* p = (char*)d_ws;
  unsigned short* xb    = (unsigned short*)p; p += (size_t)NBL*ND*2;
  unsigned short* wqb   = (unsigned short*)p; p += (size_t)ND*ND*2;
  unsigned short* wkb   = (unsigned short*)p; p += (size_t)ND*ND*2;
  unsigned short* wvb   = (unsigned short*)p; p += (size_t)ND*ND*2;
  unsigned short* wob   = (unsigned short*)p; p += (size_t)ND*ND*2;
  unsigned short* qbuf  = (unsigned short*)p; p += (size_t)NBL*ND*2;
  unsigned short* kbuf  = (unsigned short*)p; p += (size_t)NBL*ND*2;
  unsigned short* vtb   = (unsigned short*)p; p += (size_t)NBL*ND*2;
  unsigned short* opart = (unsigned short*)p; p += (size_t)2*NBL*ND*2;
  float* lsum = (float*)p; p += (size_t)2*NB*NH*NL*4;
  float2* qtab = (float2*)p; p += (size_t)NL*32*8;
  float2* ktab = (float2*)p; p += (size_t)NL*32*8;

  // 2M cvt units + 64K rope units = 8448 blocks
  hipLaunchKernelGGL(cvt_all, dim3(8448), dim3(256), 0, stream,
                     x, Wq, Wk, Wv, Wo, xb, wqb, wkb, wvb, wob, qtab, ktab);

  // NOTE the reference's swap: k uses (Wv,bv), v uses (Wk,bk)
  hipLaunchKernelGGL(gemm_qkv, dim3(NBL/128, ND/128, 3), dim3(256), 0, stream,
                     xb, wqb, bq, wvb, bv, wkb, bk, qbuf, kbuf, vtb, qtab, ktab);

  hipLaunchKernelGGL(attn_kernel, dim3(NL/256, NB*NH, 2), dim3(256), 0, stream,
                     qbuf, kbuf, vtb, opart, lsum);
  hipLaunchKernelGGL(attn_combine, dim3(NBL*ND/8/256), dim3(256), 0, stream, opart, lsum);

  hipLaunchKernelGGL(gemm_o, dim3(NBL/128, ND/64), dim3(256), 0, stream, opart, wob, bo, out);
}